// Round 5
// baseline (549.241 us; speedup 1.0000x reference)
//
#include <hip/hip_runtime.h>
#include <math.h>

#define NUM_NODES 94
#define SEQ_LEN 784
#define OUT_CLASSES 10
#define EPB 16              // batch elements per wave (MFMA N dim)
#define SP 788              // staged-input LDS stride (f32): 2-way max (free)
#define YW 100              // y stride per element in f16 units (200 B)

#define TWO_GAMMA 0.2f
#define OM2 0.0503551324598949f            // (2*pi/28)^2
#define INV_SQRT_N 0.103142124625879       // 1/sqrt(94)
#define LOG2E 1.4426950408889634
// exp2 arg = 2A*log2e -> fold 2*INV_SQRT_N*LOG2E into W, w_ih, bias (K-slots)
#define WSCALE ((float)(2.0 * INV_SQRT_N * LOG2E))

typedef _Float16 half8 __attribute__((ext_vector_type(8)));
typedef _Float16 half4 __attribute__((ext_vector_type(4)));
typedef float    floatx4 __attribute__((ext_vector_type(4)));
typedef float    f2 __attribute__((ext_vector_type(2)));

// R5: BARRIER-FREE single-wave recurrence. One wave64 owns 16 batch elements
// end-to-end: 18 MFMAs (6 row-tiles x 3 K-chunks, C-chained), 24 nodes/lane
// dynamics, y exchanged through ONE LDS buffer relying on the DS pipe's
// in-order-per-wave guarantee (reads of step t+1 are issued after writes of
// step t; no __syncthreads anywhere in the loop).
// y layout: element e at 200B stride; rows in 4-row blocks (8B), identity order.
// Writes: lane (e,h) -> blocks 4T+h. Reads: lane (e,h) -> blocks 8c+2h,+1.
// Both patterns are exactly 4 touches/bank (hardware floor, zero conflicts).
// K=96: rows 94=s_t, 95=1.0 (input+bias folded into MFMA, R4-verified math).
__global__
__attribute__((amdgpu_flat_work_group_size(64, 64), amdgpu_waves_per_eu(1, 4)))
void horn_kernel(
    const float* __restrict__ input,   // (1024, 784)
    const float* __restrict__ w_ih,    // (94, 1)
    const float* __restrict__ b_ih,    // (94)
    const float* __restrict__ w_hh,    // (94, 94)
    const float* __restrict__ b_hh,    // (94)
    const float* __restrict__ w_ro,    // (10, 94)
    const float* __restrict__ b_ro,    // (10)
    float* __restrict__ out)           // (1024, 10)
{
    __shared__ __align__(16) float    sinl[EPB * SP];   // 50,432 B (reused as xsh)
    __shared__ __align__(16) _Float16 ysh[EPB * YW];    //  3,200 B

    const int lane = threadIdx.x;      // single wave
    const int e    = lane & 15;        // element (B/D col); A row-within-tile
    const int h    = lane >> 4;        // 0..3 (k-group / D row-group)
    const int bb   = blockIdx.x;

    // ---- stage input rows to LDS (16 x 784 f32, float4-coalesced) ----
    {
        const floatx4* in4 = (const floatx4*)(input + (size_t)bb * EPB * SEQ_LEN);
        #pragma unroll 1
        for (int idx = lane; idx < EPB * (SEQ_LEN / 4); idx += 64) {
            int ee = idx / (SEQ_LEN / 4);
            int cc = idx - ee * (SEQ_LEN / 4);
            *(floatx4*)&sinl[ee * SP + 4 * cc] = in4[idx];
        }
    }

    // ---- A fragments for ALL 6 tiles (72 VGPR): rows 16T+e, cols 8h+i(+32c);
    //      K-cols 94/95 carry w_ih / bias ----
    half8 A0[6], A1[6], A2[6];
    #pragma unroll
    for (int T = 0; T < 6; ++T) {
        const int arow = 16 * T + e;
        #pragma unroll
        for (int i = 0; i < 8; ++i) {
            const int k = 8 * h + i;
            float v0 = 0.0f, v1 = 0.0f, v2 = 0.0f;
            if (arow < NUM_NODES) {
                v0 = w_hh[arow * NUM_NODES + k] * WSCALE;
                v1 = w_hh[arow * NUM_NODES + k + 32] * WSCALE;   // k+32 <= 63 < 94
                const int k2 = k + 64;
                if      (k2 <  NUM_NODES) v2 = w_hh[arow * NUM_NODES + k2] * WSCALE;
                else if (k2 == NUM_NODES) v2 = w_ih[arow] * WSCALE;                  // s_t
                else                      v2 = (b_ih[arow] + b_hh[arow]) * WSCALE;   // 1.0
            }
            A0[T][i] = (_Float16)v0; A1[T][i] = (_Float16)v1; A2[T][i] = (_Float16)v2;
        }
    }

    // ---- per-lane state: rows 16T+4h+{0,1} and {2,3}, elements e ----
    f2 X0[6], X1[6], Y0[6], Y1[6];
    #pragma unroll
    for (int T = 0; T < 6; ++T) {
        X0[T] = (f2){0.0f, 0.0f}; X1[T] = (f2){0.0f, 0.0f};
        Y0[T] = (f2){0.0f, 0.0f}; Y1[T] = (f2){0.0f, 0.0f};
    }

    // ---- init y buffer: zeros; block (T=5,h=3) = {0,0,s_0,1.0} ----
    // (read of s0 follows staging writes in the in-order DS pipe)
    const float s0 = sinl[e * SP];
    #pragma unroll
    for (int T = 0; T < 6; ++T) {
        half4 z;
        z[0] = (_Float16)0.0f; z[1] = (_Float16)0.0f;
        z[2] = (_Float16)0.0f; z[3] = (_Float16)0.0f;
        if (T == 5 && h == 3) { z[2] = (_Float16)s0; z[3] = (_Float16)1.0f; }
        *(half4*)&ysh[e * YW + 16 * T + 4 * h] = z;
    }

    const f2 no2 = {-OM2, -OM2};
    const f2 p82 = {1.0f - TWO_GAMMA, 1.0f - TWO_GAMMA};   // 0.8
    const f2 h05 = {0.5f, 0.5f};
    const floatx4 zf4 = {0.0f, 0.0f, 0.0f, 0.0f};
    const _Float16* yb = &ysh[e * YW + 8 * h];   // B-fragment base

    #pragma unroll 1
    for (int t = 0; t < SEQ_LEN; ++t) {
        // ---- read full y as B-fragments: 6x ds_read_b64, zero-conflict ----
        half4 l0 = *(const half4*)(yb);
        half4 u0 = *(const half4*)(yb + 4);
        half4 l1 = *(const half4*)(yb + 32);
        half4 u1 = *(const half4*)(yb + 36);
        half4 l2 = *(const half4*)(yb + 64);
        half4 u2 = *(const half4*)(yb + 68);
        const int tn = (t + 1 < SEQ_LEN) ? t + 1 : (SEQ_LEN - 1);
        float sn = sinl[e * SP + tn];            // s_{t+1} for the row-94 slot

        half8 B0 = __builtin_shufflevector(l0, u0, 0, 1, 2, 3, 4, 5, 6, 7);
        half8 B1 = __builtin_shufflevector(l1, u1, 0, 1, 2, 3, 4, 5, 6, 7);
        half8 B2 = __builtin_shufflevector(l2, u2, 0, 1, 2, 3, 4, 5, 6, 7);

        #pragma unroll
        for (int T = 0; T < 6; ++T) {
            // deferred-leak precompute (independent of MFMA -> fills latency)
            f2 q0 = no2 * X0[T] + h05;  q0 = p82 * Y0[T] + q0;
            f2 q1 = no2 * X1[T] + h05;  q1 = p82 * Y1[T] + q1;
            X0[T] += Y0[T];  X1[T] += Y1[T];
            // full exp2 argument via C-chained MFMAs (bias+input folded in K)
            floatx4 d = __builtin_amdgcn_mfma_f32_16x16x32_f16(A0[T], B0, zf4, 0, 0, 0);
            d = __builtin_amdgcn_mfma_f32_16x16x32_f16(A1[T], B1, d, 0, 0, 0);
            d = __builtin_amdgcn_mfma_f32_16x16x32_f16(A2[T], B2, d, 0, 0, 0);
            f2 r0, r1;
            r0[0] = __builtin_amdgcn_rcpf(__builtin_amdgcn_exp2f(d[0]) + 1.0f);
            r0[1] = __builtin_amdgcn_rcpf(__builtin_amdgcn_exp2f(d[1]) + 1.0f);
            r1[0] = __builtin_amdgcn_rcpf(__builtin_amdgcn_exp2f(d[2]) + 1.0f);
            r1[1] = __builtin_amdgcn_rcpf(__builtin_amdgcn_exp2f(d[3]) + 1.0f);
            Y0[T] = q0 - r0;  Y1[T] = q1 - r1;
            half4 yh;
            yh[0] = (_Float16)Y0[T][0]; yh[1] = (_Float16)Y0[T][1];
            yh[2] = (_Float16)Y1[T][0]; yh[3] = (_Float16)Y1[T][1];
            if (T == 5 && h == 3) {                // rows 94,95 <- s_{t+1}, 1.0
                yh[2] = (_Float16)sn; yh[3] = (_Float16)1.0f;
            }
            *(half4*)&ysh[e * YW + 16 * T + 4 * h] = yh;   // publish block 4T+h
        }
        // compiler fence: next iteration's ds_reads stay after this step's
        // ds_writes (the DS pipe's in-order guarantee does the rest)
        asm volatile("" ::: "memory");
    }

    // ---- epilogue: gather x (f32, overlay on sinl), project to classes ----
    float* xsh = sinl;
    #pragma unroll
    for (int T = 0; T < 6; ++T) {
        floatx4 xv;
        xv[0] = X0[T][0]; xv[1] = X0[T][1]; xv[2] = X1[T][0]; xv[3] = X1[T][1];
        *(floatx4*)&xsh[e * YW + 16 * T + 4 * h] = xv;
    }
    asm volatile("" ::: "memory");   // reads below stay after writes (in-order pipe)

    #pragma unroll 1
    for (int k = 0; k < 3; ++k) {
        const int idx = lane + 64 * k;
        if (idx < EPB * OUT_CLASSES) {
            const int ee = idx / OUT_CLASSES;
            const int c  = idx - ee * OUT_CLASSES;
            float acc = b_ro[c];
            #pragma unroll 2
            for (int r = 0; r < NUM_NODES; ++r)
                acc += xsh[ee * YW + r] * w_ro[c * NUM_NODES + r];
            out[((size_t)bb * EPB + ee) * OUT_CLASSES + c] = acc;
        }
    }
}

extern "C" void kernel_launch(void* const* d_in, const int* in_sizes, int n_in,
                              void* d_out, int out_size, void* d_ws, size_t ws_size,
                              hipStream_t stream) {
    const float* input = (const float*)d_in[0];
    const float* w_ih  = (const float*)d_in[1];
    const float* b_ih  = (const float*)d_in[2];
    const float* w_hh  = (const float*)d_in[3];
    const float* b_hh  = (const float*)d_in[4];
    const float* w_ro  = (const float*)d_in[5];
    const float* b_ro  = (const float*)d_in[6];
    float* out = (float*)d_out;

    const int batch = in_sizes[0] / SEQ_LEN;   // 1024
    dim3 grid(batch / EPB);                    // 64 blocks
    dim3 block(64);                            // ONE wave per block - no barriers

    hipLaunchKernelGGL(horn_kernel, grid, block, 0, stream,
                       input, w_ih, b_ih, w_hh, b_hh, w_ro, b_ro, out);
}